// Round 2
// baseline (2891.390 us; speedup 1.0000x reference)
//
#include <hip/hip_runtime.h>
#include <hip/hip_fp16.h>
#include <hip/hip_cooperative_groups.h>

namespace cg = cooperative_groups;

typedef __attribute__((ext_vector_type(8))) _Float16 half8;
typedef __attribute__((ext_vector_type(4))) _Float16 half4;
typedef __attribute__((ext_vector_type(4))) float float4v;

#define NPIX 16384  // 128*128

__device__ inline half8 h8zero() {
    half8 z = {(_Float16)0, (_Float16)0, (_Float16)0, (_Float16)0,
               (_Float16)0, (_Float16)0, (_Float16)0, (_Float16)0};
    return z;
}

struct ChainArgs {
    const float *x, *head_w, *head_b, *rb_w, *rb_b, *tail_w, *tail_b;
    const float *mw0, *mb0, *mw1, *mw2, *mw3, *mw4;
    _Float16 *pwc, *pw0, *pwm;
    float *b0p;
    _Float16 *h0, *hbuf, *tbuf, *feat;
    float *apre;
};

// ---------------- one 64->64 conv step (shifted-window implicit GEMM) ----------
// 2048 waves: nt = wave (4 couts-of-16), mt0 = blk*2 (2 m-tiles of 16 pixels).
// 18 B-fragments held in VGPRs for the whole step.
template <bool RELU, bool RES>
__device__ __forceinline__ void conv_step64(
    const _Float16* __restrict__ img, const _Float16* __restrict__ pw,
    const float* __restrict__ bias, const _Float16* __restrict__ res,
    _Float16* __restrict__ out, int blk, int wave, int lane, int q, int r)
{
    int nt = wave;
    half8 B[18];
    #pragma unroll
    for (int kc = 0; kc < 18; ++kc)
        B[kc] = *(const half8*)(pw + (((nt * 18 + kc) * 64 + lane) << 3));
    int n = (nt << 4) + r;
    float bv = bias[n];
    int mt0 = blk << 1;
    #pragma unroll
    for (int mi = 0; mi < 2; ++mi) {
        int p0 = (mt0 + mi) << 4;
        int py = p0 >> 7;
        int pxl = (p0 & 127) + r;
        float4v acc = {0.f, 0.f, 0.f, 0.f};
        #pragma unroll
        for (int kc = 0; kc < 18; ++kc) {
            int ij = kc >> 1;
            int di = ij / 3 - 1;
            int dj = ij % 3 - 1;
            int cb = ((kc & 1) << 5) + (q << 3);
            int yy = py + di, xx = pxl + dj;
            half8 a = h8zero();
            if (yy >= 0 && yy < 128 && xx >= 0 && xx < 128)
                a = *(const half8*)(img + (((yy << 7) + xx) << 6) + cb);
            acc = __builtin_amdgcn_mfma_f32_16x16x32_f16(a, B[kc], acc, 0, 0, 0);
        }
        #pragma unroll
        for (int reg = 0; reg < 4; ++reg) {
            int p = p0 + (q << 2) + reg;
            float v = acc[reg] + bv;
            if (RES) v += (float)res[(p << 6) + n];
            if (RELU) v = fmaxf(v, 0.f);
            out[(p << 6) + n] = (_Float16)v;
        }
    }
}

// step 0: all packing + head conv. steps 1..32: resblock convs. 33: tail. 34: stage-A.
__device__ void chain_step(int step, const ChainArgs& a,
                           int blk, int wave, int lane, int q, int r, int gtid)
{
    if (step == 0) {
        // pack conv weights (32 resblock convs + tail conv)
        for (int idx = gtid; idx < 33 * 36864; idx += 131072) {
            int ci = idx / 36864;
            int e  = idx % 36864;
            int j = e & 7, ln = (e >> 3) & 63, kcnt = e >> 9;
            int kc = kcnt % 18, ntc = kcnt / 18;
            int k = kc * 32 + (ln >> 4) * 8 + j;
            int nn = ntc * 16 + (ln & 15);
            int ij = k >> 6, c = k & 63;
            const float* src = (ci < 32) ? (a.rb_w + ci * 36864) : a.tail_w;
            a.pwc[idx] = (_Float16)src[(nn * 64 + c) * 9 + ij];
        }
        // pack stage-A weights (mw0[:576], N=256)
        for (int idx = gtid; idx < 147456; idx += 131072) {
            int j = idx & 7, ln = (idx >> 3) & 63, kcnt = idx >> 9;
            int kc = kcnt % 18, ntc = kcnt / 18;
            int k = kc * 32 + (ln >> 4) * 8 + j;
            int nn = ntc * 16 + (ln & 15);
            int ij = k >> 6, c = k & 63;
            a.pw0[idx] = (_Float16)a.mw0[(c * 9 + ij) * 256 + nn];
        }
        // pack mlp hidden weights + padded mw4
        for (int idx = gtid; idx < 200704; idx += 131072) {
            if (idx < 196608) {
                int l = idx / 65536;
                int e = idx % 65536;
                int j = e & 7, ln = (e >> 3) & 63, kcnt = e >> 9;
                int kc = kcnt & 7, ntc = kcnt >> 3;
                int k = kc * 32 + (ln >> 4) * 8 + j;
                int nn = ntc * 16 + (ln & 15);
                const float* w = (l == 0) ? a.mw1 : ((l == 1) ? a.mw2 : a.mw3);
                a.pwm[idx] = (_Float16)w[k * 256 + nn];
            } else {
                int e = idx - 196608;
                int j = e & 7, ln = (e >> 3) & 63, kc = e >> 9;
                int k = kc * 32 + (ln >> 4) * 8 + j;
                int nn = ln & 15;
                a.pwm[idx] = (nn < 3) ? (_Float16)a.mw4[k * 3 + nn] : (_Float16)0.0f;
            }
        }
        // b0' = mb0 + 0.5*(mw0[578] + mw0[579])
        if (gtid < 256)
            a.b0p[gtid] = a.mb0[gtid]
                        + 0.5f * (a.mw0[578 * 256 + gtid] + a.mw0[579 * 256 + gtid]);
        // head conv (Cin=3, direct fp32)
        for (int idx = gtid; idx < NPIX * 64; idx += 131072) {
            int o = idx & 63, p = idx >> 6;
            int py = p >> 7, px = p & 127;
            float acc = a.head_b[o];
            #pragma unroll
            for (int c = 0; c < 3; ++c)
                #pragma unroll
                for (int i = 0; i < 3; ++i)
                    #pragma unroll
                    for (int jj = 0; jj < 3; ++jj) {
                        int y = py + i - 1, xx = px + jj - 1;
                        if (y >= 0 && y < 128 && xx >= 0 && xx < 128)
                            acc += a.x[c * 16384 + y * 128 + xx]
                                 * a.head_w[((o * 3 + c) * 3 + i) * 3 + jj];
                    }
            a.h0[idx] = (_Float16)acc;
        }
    } else if (step <= 32) {
        int k = step - 1;
        int i = k >> 1;
        const _Float16* hin = (i == 0) ? a.h0 : a.hbuf;
        if ((k & 1) == 0) {   // conv1: relu(conv(hin)) -> tbuf
            conv_step64<true, false>(hin, a.pwc + (2 * i) * 36864, a.rb_b + i * 128,
                                     nullptr, a.tbuf, blk, wave, lane, q, r);
        } else {              // conv2: hin + conv(tbuf) -> hbuf  (elementwise-safe in place)
            conv_step64<false, true>(a.tbuf, a.pwc + (2 * i + 1) * 36864,
                                     a.rb_b + i * 128 + 64, hin, a.hbuf,
                                     blk, wave, lane, q, r);
        }
    } else if (step == 33) {  // feat = h0 + tail(hbuf)
        conv_step64<false, true>(a.hbuf, a.pwc + 32 * 36864, a.tail_b, a.h0, a.feat,
                                 blk, wave, lane, q, r);
    } else {                  // stage A: apre[cell][256] = im2col(feat) @ mw0[:576] + b0'
        int nt16 = ((blk & 3) << 2) + wave;
        int mt0 = (blk >> 2) << 3;
        half8 B[18];
        #pragma unroll
        for (int kc = 0; kc < 18; ++kc)
            B[kc] = *(const half8*)(a.pw0 + (((nt16 * 18 + kc) * 64 + lane) << 3));
        float bv = a.b0p[(nt16 << 4) + r];
        #pragma unroll 1
        for (int mi = 0; mi < 8; ++mi) {
            int p0 = (mt0 + mi) << 4;
            int py = p0 >> 7;
            int pxl = (p0 & 127) + r;
            float4v acc = {0.f, 0.f, 0.f, 0.f};
            #pragma unroll
            for (int kc = 0; kc < 18; ++kc) {
                int ij = kc >> 1;
                int di = ij / 3 - 1;
                int dj = ij % 3 - 1;
                int cb = ((kc & 1) << 5) + (q << 3);
                int yy = py + di, xx = pxl + dj;
                half8 av = h8zero();
                if (yy >= 0 && yy < 128 && xx >= 0 && xx < 128)
                    av = *(const half8*)(a.feat + (((yy << 7) + xx) << 6) + cb);
                acc = __builtin_amdgcn_mfma_f32_16x16x32_f16(av, B[kc], acc, 0, 0, 0);
            }
            #pragma unroll
            for (int reg = 0; reg < 4; ++reg) {
                int p = p0 + (q << 2) + reg;
                a.apre[((size_t)p << 8) + (nt16 << 4) + r] = acc[reg] + bv;
            }
        }
    }
}

// mode < 0: cooperative, runs all 35 steps with grid.sync between them.
// mode >= 0: non-cooperative fallback, runs just that step.
__global__ __launch_bounds__(256, 2)
void conv_chain(int mode, ChainArgs a) {
    int wave = threadIdx.x >> 6, lane = threadIdx.x & 63;
    int q = lane >> 4, r = lane & 15;
    int blk = blockIdx.x;
    int gtid = blk * 256 + threadIdx.x;
    if (mode >= 0) {
        chain_step(mode, a, blk, wave, lane, q, r, gtid);
        return;
    }
    cg::grid_group grid = cg::this_grid();
    #pragma unroll 1
    for (int s = 0; s < 35; ++s) {
        chain_step(s, a, blk, wave, lane, q, r, gtid);
        if (s < 34) grid.sync();
    }
}

// ---------------- fused LIIF MLP + ensembling (transposed MFMA) ----------------
// Block: 256 thr (4 waves) = 16 output pixels = 64 samples.
// Computes out^T = W^T (A-operand, global pack) x act^T (B-operand, LDS).
// act^T layout: element (k=feature, s=sample) at half-offset
//   (((s>>4)*8 + (k>>5))*64 + ((k>>3)&3)*16 + (s&15))*8 + (k&7)
// -> B-reads are lane-linear ds_read_b128 (conflict-free); epilogue C-writes are
//    lane-bijective 8B stores into contiguous 512B regions (conflict-free).
__global__ __launch_bounds__(256, 3)
void mlp_kernel(const float* __restrict__ apre, const float* __restrict__ mw0,
                const float* __restrict__ mb1, const float* __restrict__ mb2,
                const float* __restrict__ mb3, const float* __restrict__ mb4,
                const _Float16* __restrict__ pwm, const _Float16* __restrict__ pw4,
                float* __restrict__ out) {
    __shared__ _Float16 act[16384];        // 64 samples x 256 features, B-frag order
    __shared__ float sArea[64], sRelH[64], sRelW[64];
    __shared__ int sCell[64];
    __shared__ float sWh[256], sWw[256];

    int t = threadIdx.x;
    int bid = blockIdx.x;
    int logical = (bid & 7) * 2048 + (bid >> 3);   // XCD-contiguous pixel strips
    int p0 = logical << 4;

    if (t < 64) {
        int lp = t >> 2, rc = t & 3;
        int p = p0 + lp;
        int oh = p >> 9, ow = p & 511;
        float sh = (oh + 0.5f) * (2.0f / 512.0f) - 1.0f;
        float sw = (ow + 0.5f) * (2.0f / 512.0f) - 1.0f;
        float gh = sh + (((rc >> 1) != 0) ? (1.0f / 128.0f) : (-1.0f / 128.0f));
        float gw = sw + (((rc & 1) != 0) ? (1.0f / 128.0f) : (-1.0f / 128.0f));
        const float lim = 1.0f - 1e-6f;
        gh = fminf(fmaxf(gh, -lim), lim);
        gw = fminf(fmaxf(gw, -lim), lim);
        int iy = (int)rintf(((gh + 1.0f) * 128.0f - 1.0f) * 0.5f);  // round-half-even
        int ix = (int)rintf(((gw + 1.0f) * 128.0f - 1.0f) * 0.5f);
        iy = iy < 0 ? 0 : (iy > 127 ? 127 : iy);
        ix = ix < 0 ? 0 : (ix > 127 ? 127 : ix);
        float cy = (iy + 0.5f) * (2.0f / 128.0f) - 1.0f;
        float cx = (ix + 0.5f) * (2.0f / 128.0f) - 1.0f;
        float rh = (sh - cy) * 128.0f;
        float rw = (sw - cx) * 128.0f;
        sCell[t] = (iy << 7) + ix;
        sRelH[t] = rh; sRelW[t] = rw;
        sArea[t] = fabsf(rh * rw);
    }
    sWh[t] = mw0[576 * 256 + t];
    sWw[t] = mw0[577 * 256 + t];
    __syncthreads();

    // layer 1: act^T[k][s] = relu(A_pre[cell_s][k] + rel_h*W0[576][k] + rel_w*W0[577][k])
    {
        int s = t >> 2, fb = (t & 3) << 6;
        float rh = sRelH[s], rw = sRelW[s];
        const float* ap = apre + ((size_t)sCell[s] << 8) + fb;
        int shi = s >> 4, slo = s & 15;
        #pragma unroll
        for (int n = 0; n < 64; n += 4) {
            int f = fb + n;
            float4v ld = *(const float4v*)(ap + n);
            half4 hv;
            #pragma unroll
            for (int kk = 0; kk < 4; ++kk) {
                float v = ld[kk] + rh * sWh[f + kk] + rw * sWw[f + kk];
                hv[kk] = (_Float16)fmaxf(v, 0.0f);
            }
            *(half4*)(act + ((((shi << 3) + (f >> 5)) * 64
                              + (((f >> 3) & 3) << 4) + slo) << 3) + (f & 7)) = hv;
        }
    }
    __syncthreads();

    int wave = t >> 6, lane = t & 63, q = lane >> 4, r = lane & 15;

    // hidden layers: wave owns out-features [wave*64, wave*64+64) x all 64 samples
    float4v acc[4][4];
    #pragma unroll 1
    for (int l = 0; l < 3; ++l) {
        #pragma unroll
        for (int mti = 0; mti < 4; ++mti)
            #pragma unroll
            for (int nts = 0; nts < 4; ++nts)
                acc[mti][nts] = (float4v){0.f, 0.f, 0.f, 0.f};
        const _Float16* pw = pwm + l * 65536;
        for (int kc = 0; kc < 8; ++kc) {
            half8 A[4], Bf[4];
            #pragma unroll
            for (int mti = 0; mti < 4; ++mti)
                A[mti] = *(const half8*)(pw + ((((wave * 4 + mti) * 8 + kc) * 64 + lane) << 3));
            #pragma unroll
            for (int nts = 0; nts < 4; ++nts)
                Bf[nts] = *(const half8*)(act + ((((nts << 3) + kc) * 64 + lane) << 3));
            #pragma unroll
            for (int mti = 0; mti < 4; ++mti)
                #pragma unroll
                for (int nts = 0; nts < 4; ++nts)
                    acc[mti][nts] = __builtin_amdgcn_mfma_f32_16x16x32_f16(
                        A[mti], Bf[nts], acc[mti][nts], 0, 0, 0);
        }
        const float* mb = (l == 0) ? mb1 : ((l == 1) ? mb2 : mb3);
        float4v bv[4];
        #pragma unroll
        for (int mti = 0; mti < 4; ++mti)
            bv[mti] = *(const float4v*)(mb + (wave << 6) + mti * 16 + (q << 2));
        __syncthreads();   // all waves done reading act
        #pragma unroll
        for (int mti = 0; mti < 4; ++mti)
            #pragma unroll
            for (int nts = 0; nts < 4; ++nts) {
                // feature f = wave*64 + mti*16 + q*4 + reg, sample s = nts*16 + r
                int base = ((((nts << 3) + (wave << 1) + (mti >> 1)) * 64
                             + (((mti & 1) * 2 + (q >> 1)) << 4) + r) << 3) + ((q & 1) << 2);
                half4 hv;
                #pragma unroll
                for (int reg = 0; reg < 4; ++reg)
                    hv[reg] = (_Float16)fmaxf(acc[mti][nts][reg] + bv[mti][reg], 0.0f);
                *(half4*)(act + base) = hv;
            }
        __syncthreads();
    }

    // final layer: M=16 (3 real channels), wave w handles samples [w*16, w*16+16)
    float4v af = {0.f, 0.f, 0.f, 0.f};
    #pragma unroll
    for (int kc = 0; kc < 8; ++kc) {
        half8 A = *(const half8*)(pw4 + ((kc * 64 + lane) << 3));
        half8 Bf = *(const half8*)(act + ((((wave << 3) + kc) * 64 + lane) << 3));
        af = __builtin_amdgcn_mfma_f32_16x16x32_f16(A, Bf, af, 0, 0, 0);
    }
    // lane (q=0, r): af[reg] = pred[ch=reg][sample = wave*16 + r]
    int s = (wave << 4) + r;
    int lp = s >> 2, rc = s & 3;
    float ar = sArea[(lp << 2) + (3 - rc)];    // LIIF diagonal-swapped area
    float c0 = (af[0] + mb4[0]) * ar;
    float c1 = (af[1] + mb4[1]) * ar;
    float c2 = (af[2] + mb4[2]) * ar;
    c0 += __shfl_xor(c0, 1); c1 += __shfl_xor(c1, 1); c2 += __shfl_xor(c2, 1);
    float at = ar + __shfl_xor(ar, 1);
    c0 += __shfl_xor(c0, 2); c1 += __shfl_xor(c1, 2); c2 += __shfl_xor(c2, 2);
    at += __shfl_xor(at, 2);
    if (q == 0 && rc == 0) {
        float inv = 1.0f / (at + 1e-9f);
        out[p0 + lp]          = fminf(fmaxf(c0 * inv, 0.0f), 1.0f);
        out[262144 + p0 + lp] = fminf(fmaxf(c1 * inv, 0.0f), 1.0f);
        out[524288 + p0 + lp] = fminf(fmaxf(c2 * inv, 0.0f), 1.0f);
    }
}

extern "C" void kernel_launch(void* const* d_in, const int* in_sizes, int n_in,
                              void* d_out, int out_size, void* d_ws, size_t ws_size,
                              hipStream_t stream) {
    (void)in_sizes; (void)n_in; (void)out_size; (void)ws_size;
    ChainArgs a;
    a.x      = (const float*)d_in[0];
    a.head_w = (const float*)d_in[2];
    a.head_b = (const float*)d_in[3];
    a.rb_w   = (const float*)d_in[4];
    a.rb_b   = (const float*)d_in[5];
    a.tail_w = (const float*)d_in[6];
    a.tail_b = (const float*)d_in[7];
    a.mw0    = (const float*)d_in[8];
    a.mb0    = (const float*)d_in[9];
    a.mw1    = (const float*)d_in[10];
    const float* mb1 = (const float*)d_in[11];
    a.mw2    = (const float*)d_in[12];
    const float* mb2 = (const float*)d_in[13];
    a.mw3    = (const float*)d_in[14];
    const float* mb3 = (const float*)d_in[15];
    a.mw4    = (const float*)d_in[16];
    const float* mb4 = (const float*)d_in[17];
    float* out = (float*)d_out;

    char* w = (char*)d_ws;
    auto take = [&](size_t n) { char* p = w; w += (n + 255) & ~(size_t)255; return p; };
    a.pwc  = (_Float16*)take(33u * 36864u * 2u);
    a.pw0  = (_Float16*)take(147456u * 2u);
    a.pwm  = (_Float16*)take(200704u * 2u);
    a.b0p  = (float*)take(256u * 4u);
    a.h0   = (_Float16*)take((size_t)NPIX * 64u * 2u);
    a.hbuf = (_Float16*)take((size_t)NPIX * 64u * 2u);
    a.tbuf = (_Float16*)take((size_t)NPIX * 64u * 2u);
    a.feat = (_Float16*)take((size_t)NPIX * 64u * 2u);
    a.apre = (float*)take((size_t)NPIX * 256u * 4u);

    int mode = -1;
    void* args[] = {&mode, &a};
    hipError_t err = hipLaunchCooperativeKernel((const void*)conv_chain,
                                                dim3(512), dim3(256), args, 0, stream);
    if (err != hipSuccess) {
        // fallback: run the same steps as plain dependent dispatches
        for (int s = 0; s < 35; ++s)
            hipLaunchKernelGGL(conv_chain, dim3(512), dim3(256), 0, stream, s, a);
    }

    mlp_kernel<<<16384, 256, 0, stream>>>(a.apre, a.mw0, mb1, mb2, mb3, mb4,
                                          a.pwm, a.pwm + 196608, out);
}

// Round 3
// 807.717 us; speedup vs baseline: 3.5797x; 3.5797x over previous
//
#include <hip/hip_runtime.h>
#include <hip/hip_fp16.h>

typedef __attribute__((ext_vector_type(8))) _Float16 half8;
typedef __attribute__((ext_vector_type(4))) _Float16 half4;
typedef __attribute__((ext_vector_type(4))) float float4v;

#define NPIX 16384  // 128*128

__device__ inline half8 h8zero() {
    half8 z = {(_Float16)0, (_Float16)0, (_Float16)0, (_Float16)0,
               (_Float16)0, (_Float16)0, (_Float16)0, (_Float16)0};
    return z;
}

// ---------------- all weight packing in ONE dispatch ----------------
// ranges: [0,1216512) conv packs (32 rb convs + tail), [..,+147456) stage-A pack,
//         [..,+200704) mlp pack, [..,+256) b0p
__global__ void pack_all(const float* __restrict__ rb_w, const float* __restrict__ tail_w,
                         const float* __restrict__ mw0, const float* __restrict__ mw1,
                         const float* __restrict__ mw2, const float* __restrict__ mw3,
                         const float* __restrict__ mw4, const float* __restrict__ mb0,
                         _Float16* __restrict__ pwc, _Float16* __restrict__ pw0,
                         _Float16* __restrict__ pwm, float* __restrict__ b0p) {
    int idx = blockIdx.x * 256 + threadIdx.x;
    if (idx < 1216512) {                      // conv weights -> B-frag order
        int ci = idx / 36864;
        int e  = idx % 36864;
        int j = e & 7, ln = (e >> 3) & 63, kcnt = e >> 9;
        int kc = kcnt % 18, ntc = kcnt / 18;
        int k = kc * 32 + (ln >> 4) * 8 + j;
        int nn = ntc * 16 + (ln & 15);
        int ij = k >> 6, c = k & 63;
        const float* src = (ci < 32) ? (rb_w + ci * 36864) : tail_w;
        pwc[idx] = (_Float16)src[(nn * 64 + c) * 9 + ij];
        return;
    }
    idx -= 1216512;
    if (idx < 147456) {                       // mw0[:576] pack (N=256)
        int j = idx & 7, ln = (idx >> 3) & 63, kcnt = idx >> 9;
        int kc = kcnt % 18, ntc = kcnt / 18;
        int k = kc * 32 + (ln >> 4) * 8 + j;
        int nn = ntc * 16 + (ln & 15);
        int ij = k >> 6, c = k & 63;
        pw0[idx] = (_Float16)mw0[(c * 9 + ij) * 256 + nn];
        return;
    }
    idx -= 147456;
    if (idx < 200704) {                       // mlp hidden + padded mw4
        if (idx < 196608) {
            int l = idx / 65536;
            int e = idx % 65536;
            int j = e & 7, ln = (e >> 3) & 63, kcnt = e >> 9;
            int kc = kcnt & 7, ntc = kcnt >> 3;
            int k = kc * 32 + (ln >> 4) * 8 + j;
            int nn = ntc * 16 + (ln & 15);
            const float* w = (l == 0) ? mw1 : ((l == 1) ? mw2 : mw3);
            pwm[idx] = (_Float16)w[k * 256 + nn];
        } else {
            int e = idx - 196608;
            int j = e & 7, ln = (e >> 3) & 63, kc = e >> 9;
            int k = kc * 32 + (ln >> 4) * 8 + j;
            int nn = ln & 15;
            pwm[idx] = (nn < 3) ? (_Float16)mw4[k * 3 + nn] : (_Float16)0.0f;
        }
        return;
    }
    idx -= 200704;
    if (idx < 256)
        b0p[idx] = mb0[idx] + 0.5f * (mw0[578 * 256 + idx] + mw0[579 * 256 + idx]);
}

// ---------------- head conv (Cin=3, direct fp32) ----------------
__global__ void head_conv(const float* __restrict__ x, const float* __restrict__ w,
                          const float* __restrict__ b, _Float16* __restrict__ h0) {
    int idx = blockIdx.x * 256 + threadIdx.x;   // p*64 + o
    int o = idx & 63, p = idx >> 6;
    int py = p >> 7, px = p & 127;
    float acc = b[o];
    #pragma unroll
    for (int c = 0; c < 3; ++c)
        #pragma unroll
        for (int i = 0; i < 3; ++i)
            #pragma unroll
            for (int jj = 0; jj < 3; ++jj) {
                int y = py + i - 1, xx = px + jj - 1;
                if (y >= 0 && y < 128 && xx >= 0 && xx < 128)
                    acc += x[c * 16384 + y * 128 + xx] * w[((o * 3 + c) * 3 + i) * 3 + jj];
            }
    h0[idx] = (_Float16)acc;
}

// ---------------- fused 2-resblock kernel ----------------
// Grid 512 = 32 row-tiles x 16 col-tiles of 4x8 output pixels. Halo 4.
// LDS: IN 12x16 px (stride 72 halves = 144B, bank-spread), MID up to 10x14 px.
// Stages: c1_1 (mid1 10x14) -> c2_1 (rb1out 8x12, residual, in-place into IN)
//      -> c1_2 (mid2 6x10)  -> c2_2 (out 4x8, residual, global write).
// All intermediate values at global-OOB coords are forced to 0 (== zero padding).
#define LDS_STRIDE 72

// RES: 0 = relu -> LDS dst; 1 = +residual IN(+2,+2), write in-place IN; 2 = +residual IN(+4,+4), global out
template <int DH, int DW, int SW, int SOFF, int RES>
__device__ __forceinline__ void conv_stage(
    const _Float16* __restrict__ src, _Float16* __restrict__ dst, _Float16* __restrict__ INb,
    const _Float16* __restrict__ pw, const float* __restrict__ bias,
    int q, int r, int nb, int gy0, int gx0, _Float16* __restrict__ gout)
{
    half8 B[18];
    #pragma unroll
    for (int kc = 0; kc < 18; ++kc)
        B[kc] = *(const half8*)(pw + ((((nb >> 4) * 18 + kc) * 64 + (q << 4) + r) << 3));
    float bv = bias[nb + r];
    constexpr int NPXc = DH * DW;
    constexpr int NT = (NPXc + 15) >> 4;
    #pragma unroll 1
    for (int tl = 0; tl < NT; ++tl) {
        int pa = tl * 16 + r;                      // A-row pixel (lane r)
        int ca = pa < NPXc ? pa : NPXc - 1;
        int my = ca / DW, mx = ca % DW;
        float4v acc = {0.f, 0.f, 0.f, 0.f};
        #pragma unroll
        for (int kc = 0; kc < 18; ++kc) {
            int ij = kc >> 1;
            int di = ij / 3 - 1;
            int dj = ij % 3 - 1;
            int cb = ((kc & 1) << 5) + (q << 3);
            int sp = (my + 1 + di + SOFF) * SW + (mx + 1 + dj + SOFF);
            half8 a = *(const half8*)(src + sp * LDS_STRIDE + cb);
            acc = __builtin_amdgcn_mfma_f32_16x16x32_f16(a, B[kc], acc, 0, 0, 0);
        }
        #pragma unroll
        for (int reg = 0; reg < 4; ++reg) {
            int pc = tl * 16 + (q << 2) + reg;     // C-row pixel
            if (pc >= NPXc) continue;
            int dy = pc / DW, dx = pc % DW;
            int gy = gy0 + dy, gx = gx0 + dx;
            bool valid = (gy >= 0 && gy < 128 && gx >= 0 && gx < 128);
            if (RES == 0) {
                float v = fmaxf(acc[reg] + bv, 0.f);
                dst[pc * LDS_STRIDE + nb + r] = valid ? (_Float16)v : (_Float16)0.0f;
            } else if (RES == 1) {
                int sl = ((dy + 2) * 16 + dx + 2) * LDS_STRIDE + nb + r;
                float v = acc[reg] + bv + (float)INb[sl];
                INb[sl] = valid ? (_Float16)v : (_Float16)0.0f;
            } else {
                int sl = ((dy + 4) * 16 + dx + 4) * LDS_STRIDE + nb + r;
                float v = acc[reg] + bv + (float)INb[sl];
                gout[(((gy << 7) + gx) << 6) + nb + r] = (_Float16)v;
            }
        }
    }
}

__global__ __launch_bounds__(256, 3)
void rb_pair(const _Float16* __restrict__ img, const _Float16* __restrict__ pw,
             const float* __restrict__ bias, _Float16* __restrict__ out) {
    __shared__ _Float16 IN[192 * LDS_STRIDE];    // 12x16 px, 27.6 KB
    __shared__ _Float16 MID[140 * LDS_STRIDE];   // up to 10x14 px, 20.2 KB
    int t = threadIdx.x;
    int wave = t >> 6, lane = t & 63, q = lane >> 4, r = lane & 15;
    int tr = blockIdx.x >> 4, tc = blockIdx.x & 15;
    int ty0 = tr << 2, tx0 = tc << 3;
    int nb = wave << 4;

    // stage IN (halo 4): global rows ty0-4..ty0+7, cols tx0-4..tx0+11
    #pragma unroll
    for (int i = 0; i < 6; ++i) {
        int idx = t + i * 256;                   // 1536 = 192 px * 8 chunks
        int px = idx >> 3, c = idx & 7;
        int iy = px >> 4, ix = px & 15;
        int gy = ty0 - 4 + iy, gx = tx0 - 4 + ix;
        half8 v = h8zero();
        if (gy >= 0 && gy < 128 && gx >= 0 && gx < 128)
            v = *(const half8*)(img + (((gy << 7) + gx) << 6) + (c << 3));
        *(half8*)(IN + px * LDS_STRIDE + (c << 3)) = v;
    }
    __syncthreads();

    // rb1 conv1: mid1 = relu(conv(IN)), region 10x14 @ global (ty0-3, tx0-3)
    conv_stage<10, 14, 16, 0, 0>(IN, MID, IN, pw, bias, q, r, nb, ty0 - 3, tx0 - 3, nullptr);
    __syncthreads();
    // rb1 conv2: rb1out = IN + conv(mid1), 8x12 @ (ty0-2, tx0-2), in-place into IN(+2,+2)
    conv_stage<8, 12, 14, 0, 1>(MID, nullptr, IN, pw + 36864, bias + 64, q, r, nb,
                                ty0 - 2, tx0 - 2, nullptr);
    __syncthreads();
    // rb2 conv1: mid2 = relu(conv(rb1out)), 6x10 @ (ty0-1, tx0-1); rb1out lives in IN(+2,+2)
    conv_stage<6, 10, 16, 2, 0>(IN, MID, IN, pw + 2 * 36864, bias + 128, q, r, nb,
                                ty0 - 1, tx0 - 1, nullptr);
    __syncthreads();
    // rb2 conv2: out = rb1out + conv(mid2), 4x8 @ (ty0, tx0), residual at IN(+4,+4)
    conv_stage<4, 8, 10, 0, 2>(MID, nullptr, IN, pw + 3 * 36864, bias + 192, q, r, nb,
                               ty0, tx0, out);
}

// ---------------- unfused conv (tail + stage-A), verified round-1 version ----------
template <int NTOT, int MTPER, bool RELU, bool RES, bool F32OUT>
__global__ __launch_bounds__(256, 2)
void conv_mfma_r(const _Float16* __restrict__ img, const _Float16* __restrict__ pw,
                 const float* __restrict__ bias, const _Float16* res,
                 _Float16* outh, float* outf) {
    int wave = threadIdx.x >> 6, lane = threadIdx.x & 63;
    int q = lane >> 4, r = lane & 15;
    int nt, mt0;
    if constexpr (NTOT == 4) {
        nt = wave;
        mt0 = blockIdx.x * MTPER;
    } else {
        nt = (blockIdx.x & 3) * 4 + wave;
        mt0 = (blockIdx.x >> 2) * MTPER;
    }
    half8 B[18];
    #pragma unroll
    for (int kc = 0; kc < 18; ++kc)
        B[kc] = *(const half8*)(pw + (((nt * 18 + kc) * 64 + lane) << 3));
    int n = nt * 16 + r;
    float bv = bias[n];
    #pragma unroll
    for (int mi = 0; mi < MTPER; ++mi) {
        int mt = mt0 + mi;
        int p0 = mt * 16;
        int py = p0 >> 7;
        int pxl = (p0 & 127) + r;
        float4v acc = {0.f, 0.f, 0.f, 0.f};
        #pragma unroll
        for (int kc = 0; kc < 18; ++kc) {
            int ij = kc >> 1;
            int di = ij / 3 - 1;
            int dj = ij % 3 - 1;
            int cb = ((kc & 1) << 5) + (q << 3);
            int yy = py + di, xx = pxl + dj;
            half8 a = h8zero();
            if (yy >= 0 && yy < 128 && xx >= 0 && xx < 128)
                a = *(const half8*)(img + (((yy << 7) + xx) << 6) + cb);
            acc = __builtin_amdgcn_mfma_f32_16x16x32_f16(a, B[kc], acc, 0, 0, 0);
        }
        #pragma unroll
        for (int reg = 0; reg < 4; ++reg) {
            int p = p0 + (q << 2) + reg;
            float v = acc[reg] + bv;
            if (RES) v += (float)res[p * (NTOT * 16) + n];
            if (RELU) v = fmaxf(v, 0.f);
            if (F32OUT) outf[p * (NTOT * 16) + n] = v;
            else        outh[p * (NTOT * 16) + n] = (_Float16)v;
        }
    }
}

// ---------------- fused LIIF MLP + ensembling (transposed MFMA) ----------------
__global__ __launch_bounds__(256, 3)
void mlp_kernel(const float* __restrict__ apre, const float* __restrict__ mw0,
                const float* __restrict__ mb1, const float* __restrict__ mb2,
                const float* __restrict__ mb3, const float* __restrict__ mb4,
                const _Float16* __restrict__ pwm, const _Float16* __restrict__ pw4,
                float* __restrict__ out) {
    __shared__ _Float16 act[16384];        // 64 samples x 256 features, B-frag order
    __shared__ float sArea[64], sRelH[64], sRelW[64];
    __shared__ int sCell[64];
    __shared__ float sWh[256], sWw[256];

    int t = threadIdx.x;
    int bid = blockIdx.x;
    int logical = (bid & 7) * 2048 + (bid >> 3);   // XCD-contiguous pixel strips
    int p0 = logical << 4;

    if (t < 64) {
        int lp = t >> 2, rc = t & 3;
        int p = p0 + lp;
        int oh = p >> 9, ow = p & 511;
        float sh = (oh + 0.5f) * (2.0f / 512.0f) - 1.0f;
        float sw = (ow + 0.5f) * (2.0f / 512.0f) - 1.0f;
        float gh = sh + (((rc >> 1) != 0) ? (1.0f / 128.0f) : (-1.0f / 128.0f));
        float gw = sw + (((rc & 1) != 0) ? (1.0f / 128.0f) : (-1.0f / 128.0f));
        const float lim = 1.0f - 1e-6f;
        gh = fminf(fmaxf(gh, -lim), lim);
        gw = fminf(fmaxf(gw, -lim), lim);
        int iy = (int)rintf(((gh + 1.0f) * 128.0f - 1.0f) * 0.5f);  // round-half-even
        int ix = (int)rintf(((gw + 1.0f) * 128.0f - 1.0f) * 0.5f);
        iy = iy < 0 ? 0 : (iy > 127 ? 127 : iy);
        ix = ix < 0 ? 0 : (ix > 127 ? 127 : ix);
        float cy = (iy + 0.5f) * (2.0f / 128.0f) - 1.0f;
        float cx = (ix + 0.5f) * (2.0f / 128.0f) - 1.0f;
        float rh = (sh - cy) * 128.0f;
        float rw = (sw - cx) * 128.0f;
        sCell[t] = (iy << 7) + ix;
        sRelH[t] = rh; sRelW[t] = rw;
        sArea[t] = fabsf(rh * rw);
    }
    sWh[t] = mw0[576 * 256 + t];
    sWw[t] = mw0[577 * 256 + t];
    __syncthreads();

    // layer 1: act^T[k][s] = relu(A_pre[cell_s][k] + rel_h*W0[576][k] + rel_w*W0[577][k])
    {
        int s = t >> 2, fb = (t & 3) << 6;
        float rh = sRelH[s], rw = sRelW[s];
        const float* ap = apre + ((size_t)sCell[s] << 8) + fb;
        int shi = s >> 4, slo = s & 15;
        #pragma unroll
        for (int n = 0; n < 64; n += 4) {
            int f = fb + n;
            float4v ld = *(const float4v*)(ap + n);
            half4 hv;
            #pragma unroll
            for (int kk = 0; kk < 4; ++kk) {
                float v = ld[kk] + rh * sWh[f + kk] + rw * sWw[f + kk];
                hv[kk] = (_Float16)fmaxf(v, 0.0f);
            }
            *(half4*)(act + ((((shi << 3) + (f >> 5)) * 64
                              + (((f >> 3) & 3) << 4) + slo) << 3) + (f & 7)) = hv;
        }
    }
    __syncthreads();

    int wave = t >> 6, lane = t & 63, q = lane >> 4, r = lane & 15;

    // hidden layers: wave owns out-features [wave*64, wave*64+64) x all 64 samples
    float4v acc[4][4];
    #pragma unroll 1
    for (int l = 0; l < 3; ++l) {
        #pragma unroll
        for (int mti = 0; mti < 4; ++mti)
            #pragma unroll
            for (int nts = 0; nts < 4; ++nts)
                acc[mti][nts] = (float4v){0.f, 0.f, 0.f, 0.f};
        const _Float16* pw = pwm + l * 65536;
        for (int kc = 0; kc < 8; ++kc) {
            half8 A[4], Bf[4];
            #pragma unroll
            for (int mti = 0; mti < 4; ++mti)
                A[mti] = *(const half8*)(pw + ((((wave * 4 + mti) * 8 + kc) * 64 + lane) << 3));
            #pragma unroll
            for (int nts = 0; nts < 4; ++nts)
                Bf[nts] = *(const half8*)(act + ((((nts << 3) + kc) * 64 + lane) << 3));
            #pragma unroll
            for (int mti = 0; mti < 4; ++mti)
                #pragma unroll
                for (int nts = 0; nts < 4; ++nts)
                    acc[mti][nts] = __builtin_amdgcn_mfma_f32_16x16x32_f16(
                        A[mti], Bf[nts], acc[mti][nts], 0, 0, 0);
        }
        const float* mb = (l == 0) ? mb1 : ((l == 1) ? mb2 : mb3);
        float4v bv[4];
        #pragma unroll
        for (int mti = 0; mti < 4; ++mti)
            bv[mti] = *(const float4v*)(mb + (wave << 6) + mti * 16 + (q << 2));
        __syncthreads();   // all waves done reading act
        #pragma unroll
        for (int mti = 0; mti < 4; ++mti)
            #pragma unroll
            for (int nts = 0; nts < 4; ++nts) {
                // feature f = wave*64 + mti*16 + q*4 + reg, sample s = nts*16 + r
                int base = ((((nts << 3) + (wave << 1) + (mti >> 1)) * 64
                             + (((mti & 1) * 2 + (q >> 1)) << 4) + r) << 3) + ((q & 1) << 2);
                half4 hv;
                #pragma unroll
                for (int reg = 0; reg < 4; ++reg)
                    hv[reg] = (_Float16)fmaxf(acc[mti][nts][reg] + bv[mti][reg], 0.0f);
                *(half4*)(act + base) = hv;
            }
        __syncthreads();
    }

    // final layer: M=16 (3 real channels), wave w handles samples [w*16, w*16+16)
    float4v af = {0.f, 0.f, 0.f, 0.f};
    #pragma unroll
    for (int kc = 0; kc < 8; ++kc) {
        half8 A = *(const half8*)(pw4 + ((kc * 64 + lane) << 3));
        half8 Bf = *(const half8*)(act + ((((wave << 3) + kc) * 64 + lane) << 3));
        af = __builtin_amdgcn_mfma_f32_16x16x32_f16(A, Bf, af, 0, 0, 0);
    }
    // lane (q=0, r): af[reg] = pred[ch=reg][sample = wave*16 + r]
    int s = (wave << 4) + r;
    int lp = s >> 2, rc = s & 3;
    float ar = sArea[(lp << 2) + (3 - rc)];    // LIIF diagonal-swapped area
    float c0 = (af[0] + mb4[0]) * ar;
    float c1 = (af[1] + mb4[1]) * ar;
    float c2 = (af[2] + mb4[2]) * ar;
    c0 += __shfl_xor(c0, 1); c1 += __shfl_xor(c1, 1); c2 += __shfl_xor(c2, 1);
    float at = ar + __shfl_xor(ar, 1);
    c0 += __shfl_xor(c0, 2); c1 += __shfl_xor(c1, 2); c2 += __shfl_xor(c2, 2);
    at += __shfl_xor(at, 2);
    if (q == 0 && rc == 0) {
        float inv = 1.0f / (at + 1e-9f);
        out[p0 + lp]          = fminf(fmaxf(c0 * inv, 0.0f), 1.0f);
        out[262144 + p0 + lp] = fminf(fmaxf(c1 * inv, 0.0f), 1.0f);
        out[524288 + p0 + lp] = fminf(fmaxf(c2 * inv, 0.0f), 1.0f);
    }
}

extern "C" void kernel_launch(void* const* d_in, const int* in_sizes, int n_in,
                              void* d_out, int out_size, void* d_ws, size_t ws_size,
                              hipStream_t stream) {
    (void)in_sizes; (void)n_in; (void)out_size; (void)ws_size;
    const float* x      = (const float*)d_in[0];
    const float* head_w = (const float*)d_in[2];
    const float* head_b = (const float*)d_in[3];
    const float* rb_w   = (const float*)d_in[4];
    const float* rb_b   = (const float*)d_in[5];
    const float* tail_w = (const float*)d_in[6];
    const float* tail_b = (const float*)d_in[7];
    const float* mw0    = (const float*)d_in[8];
    const float* mb0    = (const float*)d_in[9];
    const float* mw1    = (const float*)d_in[10];
    const float* mb1    = (const float*)d_in[11];
    const float* mw2    = (const float*)d_in[12];
    const float* mb2    = (const float*)d_in[13];
    const float* mw3    = (const float*)d_in[14];
    const float* mb3    = (const float*)d_in[15];
    const float* mw4    = (const float*)d_in[16];
    const float* mb4    = (const float*)d_in[17];
    float* out = (float*)d_out;

    char* w = (char*)d_ws;
    auto take = [&](size_t n) { char* p = w; w += (n + 255) & ~(size_t)255; return p; };
    _Float16* pwc  = (_Float16*)take(33u * 36864u * 2u);
    _Float16* pw0  = (_Float16*)take(147456u * 2u);
    _Float16* pwm  = (_Float16*)take(200704u * 2u);
    float*    b0p  = (float*)take(256u * 4u);
    _Float16* h0   = (_Float16*)take((size_t)NPIX * 64u * 2u);
    _Float16* hbuf = (_Float16*)take((size_t)NPIX * 64u * 2u);
    _Float16* tbuf = (_Float16*)take((size_t)NPIX * 64u * 2u);
    _Float16* feat = (_Float16*)take((size_t)NPIX * 64u * 2u);
    float*    apre = (float*)take((size_t)NPIX * 256u * 4u);

    pack_all<<<6113, 256, 0, stream>>>(rb_w, tail_w, mw0, mw1, mw2, mw3, mw4, mb0,
                                       pwc, pw0, pwm, b0p);
    head_conv<<<4096, 256, 0, stream>>>(x, head_w, head_b, h0);

    // 8 fused 2-resblock dispatches, ping-pong hbuf/tbuf
    const _Float16* cur = h0;
    for (int p = 0; p < 8; ++p) {
        _Float16* dst = (p & 1) ? tbuf : hbuf;
        rb_pair<<<512, 256, 0, stream>>>(cur, pwc + 4 * p * 36864, rb_b + p * 256, dst);
        cur = dst;
    }
    // feat = h0 + tail(rb-chain output)   (cur == tbuf after p=7)
    conv_mfma_r<4, 2, false, true, false><<<512, 256, 0, stream>>>(
        cur, pwc + 32 * 36864, tail_b, h0, feat, nullptr);
    // stage A: apre[cell][256] = im2col(feat) @ mw0[:576] + b0'
    conv_mfma_r<16, 4, false, false, true><<<1024, 256, 0, stream>>>(
        feat, pw0, b0p, nullptr, nullptr, apre);

    mlp_kernel<<<16384, 256, 0, stream>>>(apre, mw0, mb1, mb2, mb3, mb4,
                                          pwm, pwm + 196608, out);
}

// Round 4
// 759.828 us; speedup vs baseline: 3.8053x; 1.0630x over previous
//
#include <hip/hip_runtime.h>
#include <hip/hip_fp16.h>

typedef __attribute__((ext_vector_type(8))) _Float16 half8;
typedef __attribute__((ext_vector_type(4))) _Float16 half4;
typedef __attribute__((ext_vector_type(4))) float float4v;

#define NPIX 16384  // 128*128

__device__ inline half8 h8zero() {
    half8 z = {(_Float16)0, (_Float16)0, (_Float16)0, (_Float16)0,
               (_Float16)0, (_Float16)0, (_Float16)0, (_Float16)0};
    return z;
}

// ---------------- all weight packing + head conv in ONE dispatch ----------------
// ranges: [0,1216512) conv packs (32 rb convs + tail), [+147456) stage-A pack,
//         [+200704) mlp pack, [+256) b0p, [+1048576) head conv
__global__ void pack_all(const float* __restrict__ rb_w, const float* __restrict__ tail_w,
                         const float* __restrict__ mw0, const float* __restrict__ mw1,
                         const float* __restrict__ mw2, const float* __restrict__ mw3,
                         const float* __restrict__ mw4, const float* __restrict__ mb0,
                         const float* __restrict__ x, const float* __restrict__ head_w,
                         const float* __restrict__ head_b,
                         _Float16* __restrict__ pwc, _Float16* __restrict__ pw0,
                         _Float16* __restrict__ pwm, float* __restrict__ b0p,
                         _Float16* __restrict__ h0) {
    int idx = blockIdx.x * 256 + threadIdx.x;
    if (idx < 1216512) {                      // conv weights -> B-frag order
        int ci = idx / 36864;
        int e  = idx % 36864;
        int j = e & 7, ln = (e >> 3) & 63, kcnt = e >> 9;
        int kc = kcnt % 18, ntc = kcnt / 18;
        int k = kc * 32 + (ln >> 4) * 8 + j;
        int nn = ntc * 16 + (ln & 15);
        int ij = k >> 6, c = k & 63;
        const float* src = (ci < 32) ? (rb_w + ci * 36864) : tail_w;
        pwc[idx] = (_Float16)src[(nn * 64 + c) * 9 + ij];
        return;
    }
    idx -= 1216512;
    if (idx < 147456) {                       // mw0[:576] pack (N=256)
        int j = idx & 7, ln = (idx >> 3) & 63, kcnt = idx >> 9;
        int kc = kcnt % 18, ntc = kcnt / 18;
        int k = kc * 32 + (ln >> 4) * 8 + j;
        int nn = ntc * 16 + (ln & 15);
        int ij = k >> 6, c = k & 63;
        pw0[idx] = (_Float16)mw0[(c * 9 + ij) * 256 + nn];
        return;
    }
    idx -= 147456;
    if (idx < 200704) {                       // mlp hidden + padded mw4
        if (idx < 196608) {
            int l = idx / 65536;
            int e = idx % 65536;
            int j = e & 7, ln = (e >> 3) & 63, kcnt = e >> 9;
            int kc = kcnt & 7, ntc = kcnt >> 3;
            int k = kc * 32 + (ln >> 4) * 8 + j;
            int nn = ntc * 16 + (ln & 15);
            const float* w = (l == 0) ? mw1 : ((l == 1) ? mw2 : mw3);
            pwm[idx] = (_Float16)w[k * 256 + nn];
        } else {
            int e = idx - 196608;
            int j = e & 7, ln = (e >> 3) & 63, kc = e >> 9;
            int k = kc * 32 + (ln >> 4) * 8 + j;
            int nn = ln & 15;
            pwm[idx] = (nn < 3) ? (_Float16)mw4[k * 3 + nn] : (_Float16)0.0f;
        }
        return;
    }
    idx -= 200704;
    if (idx < 256) {
        b0p[idx] = mb0[idx] + 0.5f * (mw0[578 * 256 + idx] + mw0[579 * 256 + idx]);
        return;
    }
    idx -= 256;
    if (idx < NPIX * 64) {                    // head conv (Cin=3, direct fp32)
        int o = idx & 63, p = idx >> 6;
        int py = p >> 7, px = p & 127;
        float acc = head_b[o];
        #pragma unroll
        for (int c = 0; c < 3; ++c)
            #pragma unroll
            for (int i = 0; i < 3; ++i)
                #pragma unroll
                for (int jj = 0; jj < 3; ++jj) {
                    int y = py + i - 1, xx = px + jj - 1;
                    if (y >= 0 && y < 128 && xx >= 0 && xx < 128)
                        acc += x[c * 16384 + y * 128 + xx]
                             * head_w[((o * 3 + c) * 3 + i) * 3 + jj];
                }
        h0[idx] = (_Float16)acc;
    }
}

// ---------------- fused 2-resblock kernel ----------------
// Grid 512 = 32 row-tiles x 16 col-tiles of 4x8 output pixels. Halo 4.
// LDS: IN 12x16 px (stride 72 halves = 144B, bank-spread), MID up to 10x14 px.
// All intermediate values at global-OOB coords are forced to 0 (== zero padding).
#define LDS_STRIDE 72

// RES: 0 = relu -> LDS dst; 1 = +residual IN(+2,+2), in-place; 2 = +residual IN(+4,+4), global out
template <int DH, int DW, int SW, int SOFF, int RES>
__device__ __forceinline__ void conv_stage(
    const _Float16* __restrict__ src, _Float16* __restrict__ dst, _Float16* __restrict__ INb,
    const _Float16* __restrict__ pw, const float* __restrict__ bias,
    int q, int r, int nb, int gy0, int gx0, _Float16* __restrict__ gout)
{
    half8 B[18];
    #pragma unroll
    for (int kc = 0; kc < 18; ++kc)
        B[kc] = *(const half8*)(pw + ((((nb >> 4) * 18 + kc) * 64 + (q << 4) + r) << 3));
    float bv = bias[nb + r];
    constexpr int NPXc = DH * DW;
    constexpr int NT = (NPXc + 15) >> 4;
    #pragma unroll 1
    for (int tl = 0; tl < NT; ++tl) {
        int pa = tl * 16 + r;                      // A-row pixel (lane r)
        int ca = pa < NPXc ? pa : NPXc - 1;
        int my = ca / DW, mx = ca % DW;
        float4v acc = {0.f, 0.f, 0.f, 0.f};
        #pragma unroll
        for (int kc = 0; kc < 18; ++kc) {
            int ij = kc >> 1;
            int di = ij / 3 - 1;
            int dj = ij % 3 - 1;
            int cb = ((kc & 1) << 5) + (q << 3);
            int sp = (my + 1 + di + SOFF) * SW + (mx + 1 + dj + SOFF);
            half8 a = *(const half8*)(src + sp * LDS_STRIDE + cb);
            acc = __builtin_amdgcn_mfma_f32_16x16x32_f16(a, B[kc], acc, 0, 0, 0);
        }
        #pragma unroll
        for (int reg = 0; reg < 4; ++reg) {
            int pc = tl * 16 + (q << 2) + reg;     // C-row pixel
            if (pc >= NPXc) continue;
            int dy = pc / DW, dx = pc % DW;
            int gy = gy0 + dy, gx = gx0 + dx;
            bool valid = (gy >= 0 && gy < 128 && gx >= 0 && gx < 128);
            if (RES == 0) {
                float v = fmaxf(acc[reg] + bv, 0.f);
                dst[pc * LDS_STRIDE + nb + r] = valid ? (_Float16)v : (_Float16)0.0f;
            } else if (RES == 1) {
                int sl = ((dy + 2) * 16 + dx + 2) * LDS_STRIDE + nb + r;
                float v = acc[reg] + bv + (float)INb[sl];
                INb[sl] = valid ? (_Float16)v : (_Float16)0.0f;
            } else {
                int sl = ((dy + 4) * 16 + dx + 4) * LDS_STRIDE + nb + r;
                float v = acc[reg] + bv + (float)INb[sl];
                gout[(((gy << 7) + gx) << 6) + nb + r] = (_Float16)v;
            }
        }
    }
}

__global__ __launch_bounds__(256, 3)
void rb_pair(const _Float16* __restrict__ img, const _Float16* __restrict__ pw,
             const float* __restrict__ bias, _Float16* __restrict__ out) {
    __shared__ _Float16 IN[192 * LDS_STRIDE];    // 12x16 px, 27.6 KB
    __shared__ _Float16 MID[140 * LDS_STRIDE];   // up to 10x14 px, 20.2 KB
    int t = threadIdx.x;
    int wave = t >> 6, lane = t & 63, q = lane >> 4, r = lane & 15;
    int tr = blockIdx.x >> 4, tc = blockIdx.x & 15;
    int ty0 = tr << 2, tx0 = tc << 3;
    int nb = wave << 4;

    // stage IN (halo 4): global rows ty0-4..ty0+7, cols tx0-4..tx0+11
    #pragma unroll
    for (int i = 0; i < 6; ++i) {
        int idx = t + i * 256;                   // 1536 = 192 px * 8 chunks
        int px = idx >> 3, c = idx & 7;
        int iy = px >> 4, ix = px & 15;
        int gy = ty0 - 4 + iy, gx = tx0 - 4 + ix;
        half8 v = h8zero();
        if (gy >= 0 && gy < 128 && gx >= 0 && gx < 128)
            v = *(const half8*)(img + (((gy << 7) + gx) << 6) + (c << 3));
        *(half8*)(IN + px * LDS_STRIDE + (c << 3)) = v;
    }
    __syncthreads();

    conv_stage<10, 14, 16, 0, 0>(IN, MID, IN, pw, bias, q, r, nb, ty0 - 3, tx0 - 3, nullptr);
    __syncthreads();
    conv_stage<8, 12, 14, 0, 1>(MID, nullptr, IN, pw + 36864, bias + 64, q, r, nb,
                                ty0 - 2, tx0 - 2, nullptr);
    __syncthreads();
    conv_stage<6, 10, 16, 2, 0>(IN, MID, IN, pw + 2 * 36864, bias + 128, q, r, nb,
                                ty0 - 1, tx0 - 1, nullptr);
    __syncthreads();
    conv_stage<4, 8, 10, 0, 2>(MID, nullptr, IN, pw + 3 * 36864, bias + 192, q, r, nb,
                               ty0, tx0, out);
}

// ---------------- unfused conv (tail + stage-A) ----------
template <int NTOT, int MTPER, bool RELU, bool RES, bool F32OUT>
__global__ __launch_bounds__(256, 2)
void conv_mfma_r(const _Float16* __restrict__ img, const _Float16* __restrict__ pw,
                 const float* __restrict__ bias, const _Float16* res,
                 _Float16* outh, float* outf) {
    int wave = threadIdx.x >> 6, lane = threadIdx.x & 63;
    int q = lane >> 4, r = lane & 15;
    int nt, mt0;
    if constexpr (NTOT == 4) {
        nt = wave;
        mt0 = blockIdx.x * MTPER;
    } else {
        nt = (blockIdx.x & 3) * 4 + wave;
        mt0 = (blockIdx.x >> 2) * MTPER;
    }
    half8 B[18];
    #pragma unroll
    for (int kc = 0; kc < 18; ++kc)
        B[kc] = *(const half8*)(pw + (((nt * 18 + kc) * 64 + lane) << 3));
    int n = nt * 16 + r;
    float bv = bias[n];
    #pragma unroll
    for (int mi = 0; mi < MTPER; ++mi) {
        int mt = mt0 + mi;
        int p0 = mt * 16;
        int py = p0 >> 7;
        int pxl = (p0 & 127) + r;
        float4v acc = {0.f, 0.f, 0.f, 0.f};
        #pragma unroll
        for (int kc = 0; kc < 18; ++kc) {
            int ij = kc >> 1;
            int di = ij / 3 - 1;
            int dj = ij % 3 - 1;
            int cb = ((kc & 1) << 5) + (q << 3);
            int yy = py + di, xx = pxl + dj;
            half8 a = h8zero();
            if (yy >= 0 && yy < 128 && xx >= 0 && xx < 128)
                a = *(const half8*)(img + (((yy << 7) + xx) << 6) + cb);
            acc = __builtin_amdgcn_mfma_f32_16x16x32_f16(a, B[kc], acc, 0, 0, 0);
        }
        #pragma unroll
        for (int reg = 0; reg < 4; ++reg) {
            int p = p0 + (q << 2) + reg;
            float v = acc[reg] + bv;
            if (RES) v += (float)res[p * (NTOT * 16) + n];
            if (RELU) v = fmaxf(v, 0.f);
            if (F32OUT) outf[p * (NTOT * 16) + n] = v;
            else        outh[p * (NTOT * 16) + n] = (_Float16)v;
        }
    }
}

// ---------------- fused LIIF MLP + ensembling ----------------
// Block: 256 thr (4 waves) = 16 output pixels = 64 samples (s = lp*4 + rc).
// act in LDS, FRAGMENT-MAJOR layout: element (row,col) at half-offset
//   (((row>>4)*8 + (col>>5))*64 + ((col>>3)&3)*16 + (row&15))*8 + (col&7)
// A-frag reads AND layer-1 staging writes are both lane-linear (conflict-free).
__global__ __launch_bounds__(256, 4)
void mlp_kernel(const float* __restrict__ apre, const float* __restrict__ mw0,
                const float* __restrict__ mb1, const float* __restrict__ mb2,
                const float* __restrict__ mb3, const float* __restrict__ mb4,
                const _Float16* __restrict__ pwm, const _Float16* __restrict__ pw4,
                float* __restrict__ out) {
    __shared__ _Float16 act[16384];        // 64 x 256, fragment-major (32 KB)
    __shared__ float sArea[64], sRelH[64], sRelW[64];
    __shared__ int sCell[64];
    __shared__ float sWh[256], sWw[256];

    int t = threadIdx.x;
    int bid = blockIdx.x;
    int logical = (bid & 7) * 2048 + (bid >> 3);   // XCD-contiguous pixel strips
    int p0 = logical << 4;

    if (t < 64) {
        int lp = t >> 2, rc = t & 3;
        int p = p0 + lp;
        int oh = p >> 9, ow = p & 511;
        float sh = (oh + 0.5f) * (2.0f / 512.0f) - 1.0f;
        float sw = (ow + 0.5f) * (2.0f / 512.0f) - 1.0f;
        float gh = sh + (((rc >> 1) != 0) ? (1.0f / 128.0f) : (-1.0f / 128.0f));
        float gw = sw + (((rc & 1) != 0) ? (1.0f / 128.0f) : (-1.0f / 128.0f));
        const float lim = 1.0f - 1e-6f;
        gh = fminf(fmaxf(gh, -lim), lim);
        gw = fminf(fmaxf(gw, -lim), lim);
        int iy = (int)rintf(((gh + 1.0f) * 128.0f - 1.0f) * 0.5f);  // round-half-even
        int ix = (int)rintf(((gw + 1.0f) * 128.0f - 1.0f) * 0.5f);
        iy = iy < 0 ? 0 : (iy > 127 ? 127 : iy);
        ix = ix < 0 ? 0 : (ix > 127 ? 127 : ix);
        float cy = (iy + 0.5f) * (2.0f / 128.0f) - 1.0f;
        float cx = (ix + 0.5f) * (2.0f / 128.0f) - 1.0f;
        float rh = (sh - cy) * 128.0f;
        float rw = (sw - cx) * 128.0f;
        sCell[t] = (iy << 7) + ix;
        sRelH[t] = rh; sRelW[t] = rw;
        sArea[t] = fabsf(rh * rw);
    }
    sWh[t] = mw0[576 * 256 + t];
    sWw[t] = mw0[577 * 256 + t];
    __syncthreads();

    int wave = t >> 6, lane = t & 63, q = lane >> 4, r = lane & 15;

    // layer 1: lane-linear staging. Thread (wave,lane) handles sample
    // s = wave*16 + (lane&15), features f = j*32 + (lane>>4)*8 .. +8, j=0..7.
    // Write chunk index = (wave*8+j)*64 + lane  ->  consecutive lanes, consecutive 16B.
    {
        int s = (wave << 4) + r;
        float rh = sRelH[s], rw = sRelW[s];
        const float* ap = apre + ((size_t)sCell[s] << 8) + (q << 3);
        #pragma unroll
        for (int j = 0; j < 8; ++j) {
            int f0 = (j << 5) + (q << 3);
            float4v lo = *(const float4v*)(ap + (j << 5));
            float4v hi = *(const float4v*)(ap + (j << 5) + 4);
            half8 hv;
            #pragma unroll
            for (int kk = 0; kk < 4; ++kk) {
                float v = lo[kk] + rh * sWh[f0 + kk] + rw * sWw[f0 + kk];
                hv[kk] = (_Float16)fmaxf(v, 0.0f);
            }
            #pragma unroll
            for (int kk = 0; kk < 4; ++kk) {
                float v = hi[kk] + rh * sWh[f0 + 4 + kk] + rw * sWw[f0 + 4 + kk];
                hv[4 + kk] = (_Float16)fmaxf(v, 0.0f);
            }
            *(half8*)(act + ((((wave << 3) + j) * 64 + lane) << 3)) = hv;
        }
    }
    __syncthreads();

    // hidden layers: each wave does all 64 rows x its 64-col quarter (4x4 frag tiles)
    float4v acc[4][4];
    #pragma unroll 1
    for (int l = 0; l < 3; ++l) {
        #pragma unroll
        for (int mt = 0; mt < 4; ++mt)
            #pragma unroll
            for (int nt = 0; nt < 4; ++nt)
                acc[mt][nt] = (float4v){0.f, 0.f, 0.f, 0.f};
        const _Float16* pw = pwm + l * 65536;
        for (int kc = 0; kc < 8; ++kc) {
            half8 A[4], B[4];
            #pragma unroll
            for (int mt = 0; mt < 4; ++mt)
                A[mt] = *(const half8*)(act + (((mt * 8 + kc) * 64 + lane) << 3));
            #pragma unroll
            for (int nt = 0; nt < 4; ++nt)
                B[nt] = *(const half8*)(pw + ((((wave * 4 + nt) * 8 + kc) * 64 + lane) << 3));
            #pragma unroll
            for (int mt = 0; mt < 4; ++mt)
                #pragma unroll
                for (int nt = 0; nt < 4; ++nt)
                    acc[mt][nt] = __builtin_amdgcn_mfma_f32_16x16x32_f16(
                        A[mt], B[nt], acc[mt][nt], 0, 0, 0);
        }
        const float* mb = (l == 0) ? mb1 : ((l == 1) ? mb2 : mb3);
        float bv[4];
        #pragma unroll
        for (int nt = 0; nt < 4; ++nt)
            bv[nt] = mb[(wave << 6) + nt * 16 + r];
        __syncthreads();   // all waves done reading act
        #pragma unroll
        for (int mt = 0; mt < 4; ++mt)
            #pragma unroll
            for (int nt = 0; nt < 4; ++nt) {
                // out row = mt*16 + q*4 + reg, col = wave*64 + nt*16 + r
                int kcp = (wave << 1) + (nt >> 1);
                int qp  = ((nt & 1) << 1) + (r >> 3);
                int base = ((mt * 8 + kcp) * 64 + qp * 16 + (q << 2)) * 8 + (r & 7);
                #pragma unroll
                for (int reg = 0; reg < 4; ++reg) {
                    float v = fmaxf(acc[mt][nt][reg] + bv[nt], 0.0f);
                    act[base + reg * 8] = (_Float16)v;
                }
            }
        __syncthreads();
    }

    // final layer: wave handles rows 16w..16w+15; D rows = 4 samples of pixel (wave*4+q)
    float4v af = {0.f, 0.f, 0.f, 0.f};
    #pragma unroll
    for (int kc = 0; kc < 8; ++kc) {
        half8 A = *(const half8*)(act + (((wave * 8 + kc) * 64 + lane) << 3));
        half8 B = *(const half8*)(pw4 + ((kc * 64 + lane) << 3));
        af = __builtin_amdgcn_mfma_f32_16x16x32_f16(A, B, af, 0, 0, 0);
    }
    if (r < 3) {   // reg rc holds pred[pixel=wave*4+q][rc][ch=r]
        float b4 = mb4[r];
        int lp = (wave << 2) + q;
        float a0 = sArea[lp * 4 + 0], a1 = sArea[lp * 4 + 1];
        float a2 = sArea[lp * 4 + 2], a3 = sArea[lp * 4 + 3];
        float tot = a0 + a1 + a2 + a3 + 1e-9f;
        float num = (af[0] + b4) * a3 + (af[1] + b4) * a2
                  + (af[2] + b4) * a1 + (af[3] + b4) * a0;
        float v = num / tot;
        v = fminf(fmaxf(v, 0.0f), 1.0f);
        out[r * 262144 + p0 + lp] = v;
    }
}

extern "C" void kernel_launch(void* const* d_in, const int* in_sizes, int n_in,
                              void* d_out, int out_size, void* d_ws, size_t ws_size,
                              hipStream_t stream) {
    (void)in_sizes; (void)n_in; (void)out_size; (void)ws_size;
    const float* x      = (const float*)d_in[0];
    const float* head_w = (const float*)d_in[2];
    const float* head_b = (const float*)d_in[3];
    const float* rb_w   = (const float*)d_in[4];
    const float* rb_b   = (const float*)d_in[5];
    const float* tail_w = (const float*)d_in[6];
    const float* tail_b = (const float*)d_in[7];
    const float* mw0    = (const float*)d_in[8];
    const float* mb0    = (const float*)d_in[9];
    const float* mw1    = (const float*)d_in[10];
    const float* mb1    = (const float*)d_in[11];
    const float* mw2    = (const float*)d_in[12];
    const float* mb2    = (const float*)d_in[13];
    const float* mw3    = (const float*)d_in[14];
    const float* mb3    = (const float*)d_in[15];
    const float* mw4    = (const float*)d_in[16];
    const float* mb4    = (const float*)d_in[17];
    float* out = (float*)d_out;

    char* w = (char*)d_ws;
    auto take = [&](size_t n) { char* p = w; w += (n + 255) & ~(size_t)255; return p; };
    _Float16* pwc  = (_Float16*)take(33u * 36864u * 2u);
    _Float16* pw0  = (_Float16*)take(147456u * 2u);
    _Float16* pwm  = (_Float16*)take(200704u * 2u);
    float*    b0p  = (float*)take(256u * 4u);
    _Float16* h0   = (_Float16*)take((size_t)NPIX * 64u * 2u);
    _Float16* hbuf = (_Float16*)take((size_t)NPIX * 64u * 2u);
    _Float16* tbuf = (_Float16*)take((size_t)NPIX * 64u * 2u);
    _Float16* feat = (_Float16*)take((size_t)NPIX * 64u * 2u);
    float*    apre = (float*)take((size_t)NPIX * 256u * 4u);

    // 10209 blocks covers packs + b0p + head conv
    pack_all<<<10209, 256, 0, stream>>>(rb_w, tail_w, mw0, mw1, mw2, mw3, mw4, mb0,
                                        x, head_w, head_b, pwc, pw0, pwm, b0p, h0);

    // 8 fused 2-resblock dispatches, ping-pong hbuf/tbuf
    const _Float16* cur = h0;
    for (int p = 0; p < 8; ++p) {
        _Float16* dst = (p & 1) ? tbuf : hbuf;
        rb_pair<<<512, 256, 0, stream>>>(cur, pwc + 4 * p * 36864, rb_b + p * 256, dst);
        cur = dst;
    }
    // feat = h0 + tail(rb-chain output)
    conv_mfma_r<4, 2, false, true, false><<<512, 256, 0, stream>>>(
        cur, pwc + 32 * 36864, tail_b, h0, feat, nullptr);
    // stage A: apre[cell][256] = im2col(feat) @ mw0[:576] + b0'
    conv_mfma_r<16, 4, false, false, true><<<1024, 256, 0, stream>>>(
        feat, pw0, b0p, nullptr, nullptr, apre);

    mlp_kernel<<<16384, 256, 0, stream>>>(apre, mw0, mb1, mb2, mb3, mb4,
                                          pwm, pwm + 196608, out);
}